// Round 2
// baseline (316.466 us; speedup 1.0000x reference)
//
#include <hip/hip_runtime.h>
#include <hip/hip_bf16.h>
#include <math.h>

#define B 32
#define S 1024
#define IN_DIM 16
#define E 128
#define NH 4
#define DH 32
#define HDIM 256
#define ROWS (B*S)   /* 32768 */
#define EPS 1e-5f

#define N_IPW (3*384*128)
#define N_SQ  (3*128*128)
#define NCVT ((N_IPW + 3*N_SQ) / 256)   /* 1152 cvt blocks */

typedef __bf16 bf16x8 __attribute__((ext_vector_type(8)));
typedef __bf16 bf16x4 __attribute__((ext_vector_type(4)));
typedef __bf16 bf16x2 __attribute__((ext_vector_type(2)));
typedef float f32x4 __attribute__((ext_vector_type(4)));

#define MFMA16 __builtin_amdgcn_mfma_f32_16x16x32_bf16

union BF2U { bf16x2 b; unsigned int u; };
__device__ inline unsigned int pk2(float a, float b) {
    BF2U x; x.b[0] = (__bf16)a; x.b[1] = (__bf16)b; return x.u;
}

// 16B logical access as two 8B LDS ops (rows padded to RP%8==4 elems are only
// 8B-aligned; RP%8==4 makes every hot pattern exactly 4 dwords/bank).
union U8 { bf16x8 v8; bf16x4 v4[2]; };
__device__ inline void st8(__bf16* p, bf16x8 v) {
    U8 u; u.v8 = v;
    *(bf16x4*)p = u.v4[0];
    *(bf16x4*)(p + 4) = u.v4[1];
}
__device__ inline bf16x8 ld8(const __bf16* p) {
    U8 u;
    u.v4[0] = *(const bf16x4*)p;
    u.v4[1] = *(const bf16x4*)(p + 4);
    return u.v8;
}

// ---------------- fused weight-cvt + embed ----------------
__global__ __launch_bounds__(256) void k_embedcvt(
        const float* __restrict__ ipw, const float* __restrict__ ow,
        const float* __restrict__ w1, const float* __restrict__ w2,
        __bf16* __restrict__ wbo,
        const float* __restrict__ x, const float* __restrict__ W,
        const float* __restrict__ bias, __bf16* __restrict__ hb)
{
    int t = threadIdx.x;
    if (blockIdx.x < NCVT) {
        int i = blockIdx.x * 256 + t;
        float v;
        if (i < N_IPW) v = ipw[i];
        else if (i < N_IPW + N_SQ) v = ow[i - N_IPW];
        else if (i < N_IPW + 2 * N_SQ) v = w1[i - N_IPW - N_SQ];
        else v = w2[i - N_IPW - 2 * N_SQ];
        wbo[i] = (__bf16)v;
        return;
    }
    int row0 = (blockIdx.x - NCVT) * 16;
    __shared__ float xs[16][16];
    xs[t >> 4][t & 15] = x[(row0 + (t >> 4)) * IN_DIM + (t & 15)];
    __syncthreads();
    int sub = t >> 7, tc = t & 127;
    float w[16];
#pragma unroll
    for (int i = 0; i < 16; ++i) w[i] = W[tc * 16 + i];
    float bb = bias[tc];
#pragma unroll
    for (int rr = 0; rr < 8; ++rr) {
        int lr = sub * 8 + rr;
        float acc = bb;
#pragma unroll
        for (int i = 0; i < 16; ++i) acc += xs[lr][i] * w[i];
        hb[(size_t)(row0 + lr) * E + tc] = (__bf16)fmaxf(acc, 0.f);
    }
}

// ---------------- fused QKV-projection + flash attention (16-wave) ----------------
// R2: 1024 threads = 16 waves = 4 waves/SIMD (was 2 — kernel was latency-bound
// at Occupancy 16.7%). Each wave owns 32 q-rows (2 qf). Pm is a half-width
// per-wave slot [16][36]: per qf the transpose runs in two 32-col halves
// (wr ck01 -> rd kc0 -> wr ck23 -> rd kc1), relying on same-wave in-order LDS
// (the R1 kernel already depends on this for Pm reuse). LDS 158.5 KB.
__global__ __launch_bounds__(1024, 4) void k_qkvattn(
        const __bf16* __restrict__ hb, const __bf16* __restrict__ Wip,
        const float* __restrict__ bip, __bf16* __restrict__ O)
{
    __shared__ __attribute__((aligned(16))) __bf16 Ksh[1024][36];
    __shared__ __attribute__((aligned(16))) __bf16 Vsh[32][1036];
    __shared__ __attribute__((aligned(16))) __bf16 Pm[16][16][36];

    int t = threadIdx.x, lane = t & 63, wv = t >> 6;   // wv 0..15
    int l15 = lane & 15, quad = lane >> 4;
    // XCD grouping: all 8 blocks sharing a b-panel land on the same XCD.
    int lb = ((blockIdx.x & 7) << 5) | (blockIdx.x >> 3);
    int half = lb & 1, bh = lb >> 1;
    int hh = bh & 3, b = bh >> 2;

    const __bf16* hpanel = hb + (size_t)b * S * E;

    // scale * log2(e) * 2^23 (Schraudolph pre-scale)
    const float qscale = 0.1767766952966369f * 1.4426950408889634f * 8388608.0f;
    const float C2 = 1065101558.0f;   // (127<<23) - 0.03*2^23
    const f32x4 cinit = {C2, C2, C2, C2};
    const f32x4 z4 = {0.f, 0.f, 0.f, 0.f};

    // ---------- phase 1: Q for this wave's 32 rows (2 qf) ----------
    int qrow0 = half * 512 + wv * 32;
    bf16x8 bQ[2];
    {
        bf16x8 bWq[2][4];
#pragma unroll
        for (int df = 0; df < 2; ++df)
#pragma unroll
            for (int kc = 0; kc < 4; ++kc)
                bWq[df][kc] = *(const bf16x8*)&Wip[(size_t)(hh*32 + df*16 + l15)*128 + kc*32 + quad*8];
        float bq0 = bip[hh*32 + l15], bq1 = bip[hh*32 + 16 + l15];
#pragma unroll
        for (int qf = 0; qf < 2; ++qf) {
            bf16x8 af[4];
#pragma unroll
            for (int kc = 0; kc < 4; ++kc)
                af[kc] = *(const bf16x8*)&hpanel[(size_t)(qrow0 + qf*16 + l15)*128 + kc*32 + quad*8];
            f32x4 a0 = z4, a1 = z4;
#pragma unroll
            for (int kc = 0; kc < 4; ++kc) {
                a0 = MFMA16(af[kc], bWq[0][kc], a0, 0, 0, 0);
                a1 = MFMA16(af[kc], bWq[1][kc], a1, 0, 0, 0);
            }
            // transpose D[q][d] (lane=d) -> B-layout (lane=q) via private Pm
#pragma unroll
            for (int r = 0; r < 4; ++r) {
                Pm[wv][quad*4 + r][l15]      = (__bf16)((a0[r] + bq0) * qscale);
                Pm[wv][quad*4 + r][16 + l15] = (__bf16)((a1[r] + bq1) * qscale);
            }
            __asm__ __volatile__("" ::: "memory");
            bQ[qf] = ld8(&Pm[wv][l15][quad*8]);
            __asm__ __volatile__("" ::: "memory");
        }
    }

    // ---------- phase 2: K,V projection into LDS (barrier-free) ----------
    {
        bf16x8 bWk[2][4], bWv[2][4];
#pragma unroll
        for (int df = 0; df < 2; ++df)
#pragma unroll
            for (int kc = 0; kc < 4; ++kc) {
                bWk[df][kc] = *(const bf16x8*)&Wip[(size_t)(128 + hh*32 + df*16 + l15)*128 + kc*32 + quad*8];
                bWv[df][kc] = *(const bf16x8*)&Wip[(size_t)(256 + hh*32 + df*16 + l15)*128 + kc*32 + quad*8];
            }
        float bk0 = bip[128 + hh*32 + l15],  bk1 = bip[128 + hh*32 + 16 + l15];
        float bvb0 = bip[256 + hh*32 + l15], bvb1 = bip[256 + hh*32 + 16 + l15];
#pragma unroll
        for (int c = 0; c < 4; ++c) {
            int srow = c*256 + wv*16 + l15;   // 16 waves x 16 rows = 256 s/iter
            bf16x8 af[4];
#pragma unroll
            for (int kc = 0; kc < 4; ++kc)
                af[kc] = *(const bf16x8*)&hpanel[(size_t)srow*128 + kc*32 + quad*8];
            f32x4 k0 = z4, k1 = z4, v0 = z4, v1 = z4;
#pragma unroll
            for (int kc = 0; kc < 4; ++kc) {
                k0 = MFMA16(af[kc], bWk[0][kc], k0, 0, 0, 0);
                k1 = MFMA16(af[kc], bWk[1][kc], k1, 0, 0, 0);
                v0 = MFMA16(af[kc], bWv[0][kc], v0, 0, 0, 0);
                v1 = MFMA16(af[kc], bWv[1][kc], v1, 0, 0, 0);
            }
            int s0 = c*256 + wv*16 + quad*4;
#pragma unroll
            for (int r = 0; r < 4; ++r) {
                Ksh[s0 + r][l15]      = (__bf16)(k0[r] + bk0);
                Ksh[s0 + r][16 + l15] = (__bf16)(k1[r] + bk1);
            }
            uint2 u0, u1;
            u0.x = pk2(v0[0] + bvb0, v0[1] + bvb0);
            u0.y = pk2(v0[2] + bvb0, v0[3] + bvb0);
            u1.x = pk2(v1[0] + bvb1, v1[1] + bvb1);
            u1.y = pk2(v1[2] + bvb1, v1[3] + bvb1);
            *(uint2*)&Vsh[l15][s0] = u0;
            *(uint2*)&Vsh[16 + l15][s0] = u1;
        }
    }
    __syncthreads();

    // ---------- phase 3: attention, K/V LDS-resident, no barriers ----------
    bf16x8 vones;
#pragma unroll
    for (int j = 0; j < 8; ++j) vones[j] = (__bf16)1.0f;
    f32x4 o[2][2], ol[2];
#pragma unroll
    for (int qf = 0; qf < 2; ++qf) {
        ol[qf] = z4; o[qf][0] = z4; o[qf][1] = z4;
    }

    for (int c = 0; c < 16; ++c) {
        bf16x8 aK[4], bV[2][2];
#pragma unroll
        for (int ck = 0; ck < 4; ++ck)
            aK[ck] = ld8(&Ksh[c*64 + ck*16 + l15][quad*8]);
#pragma unroll
        for (int kc = 0; kc < 2; ++kc) {
            bV[kc][0] = ld8(&Vsh[l15][c*64 + kc*32 + quad*8]);
            bV[kc][1] = ld8(&Vsh[16 + l15][c*64 + kc*32 + quad*8]);
        }
#pragma unroll
        for (int qf = 0; qf < 2; ++qf) {
            f32x4 sf[4];
#pragma unroll
            for (int ck = 0; ck < 4; ++ck)
                sf[ck] = MFMA16(aK[ck], bQ[qf], cinit, 0, 0, 0);
            uint2 u[4];
#pragma unroll
            for (int ck = 0; ck < 4; ++ck) {
                int i0 = (int)sf[ck][0];
                int i1 = (int)sf[ck][1];
                int i2 = (int)sf[ck][2];
                int i3 = (int)sf[ck][3];
                u[ck].x = __builtin_amdgcn_perm((unsigned)i1, (unsigned)i0, 0x07060302u);
                u[ck].y = __builtin_amdgcn_perm((unsigned)i3, (unsigned)i2, 0x07060302u);
            }
            // half A: P s-cols 0..31 of this c-chunk
            *(uint2*)&Pm[wv][l15][quad*4]      = u[0];
            *(uint2*)&Pm[wv][l15][16 + quad*4] = u[1];
            __asm__ __volatile__("" ::: "memory");
            {
                bf16x8 ap = ld8(&Pm[wv][l15][quad*8]);
                o[qf][0] = MFMA16(ap, bV[0][0], o[qf][0], 0, 0, 0);
                o[qf][1] = MFMA16(ap, bV[0][1], o[qf][1], 0, 0, 0);
                ol[qf]   = MFMA16(ap, vones, ol[qf], 0, 0, 0);
            }
            __asm__ __volatile__("" ::: "memory");
            // half B: P s-cols 32..63 (same-wave in-order LDS: write lands
            // after the preceding read of the same addresses)
            *(uint2*)&Pm[wv][l15][quad*4]      = u[2];
            *(uint2*)&Pm[wv][l15][16 + quad*4] = u[3];
            __asm__ __volatile__("" ::: "memory");
            {
                bf16x8 ap = ld8(&Pm[wv][l15][quad*8]);
                o[qf][0] = MFMA16(ap, bV[1][0], o[qf][0], 0, 0, 0);
                o[qf][1] = MFMA16(ap, bV[1][1], o[qf][1], 0, 0, 0);
                ol[qf]   = MFMA16(ap, vones, ol[qf], 0, 0, 0);
            }
            __asm__ __volatile__("" ::: "memory");
        }
    }

    // ---------- epilogue ----------
#pragma unroll
    for (int qf = 0; qf < 2; ++qf)
#pragma unroll
        for (int r = 0; r < 4; ++r) {
            float linv = 1.f / ol[qf][r];
            int row = half*512 + wv*32 + qf*16 + quad*4 + r;
            __bf16* op = O + ((size_t)(b * S) + row) * E + hh*32;
            op[l15]      = (__bf16)(o[qf][0][r] * linv);
            op[16 + l15] = (__bf16)(o[qf][1][r] * linv);
        }
}

// ---------------- mega-fused: out-proj + res + LN1 + FFN1 + FFN2 + res + LN2 ----------------
// R2: 512 threads = 8 waves; each wave 16 rows x 64 cols. Grid 512 -> 2
// blocks/CU -> 16 waves/CU = 4 waves/SIMD (was 2).
__global__ __launch_bounds__(512, 4) void k_layer2(const __bf16* __restrict__ t0b,
        const __bf16* __restrict__ Wo, const float* __restrict__ ob,
        const float* __restrict__ g1, const float* __restrict__ bt1,
        const __bf16* __restrict__ W1, const float* __restrict__ b1v,
        const __bf16* __restrict__ W2, const float* __restrict__ b2v,
        const float* __restrict__ g2, const float* __restrict__ bt2,
        __bf16* __restrict__ hb)
{
    __shared__ __attribute__((aligned(16))) __bf16 As[64][132];
    __shared__ __attribute__((aligned(16))) __bf16 Ws[128][132];
    __shared__ float red[2][64][2];
    int t = threadIdx.x;
    int m0 = blockIdx.x * 64;
    int arow = t >> 3, acol = (t & 7) * 16;
    int wrow = t >> 2, wcol = (t & 3) * 32;
    {
        const __bf16* Ap = t0b + (size_t)(m0 + arow) * 128 + acol;
#pragma unroll
        for (int j = 0; j < 2; ++j)
            st8(&As[arow][acol + j * 8], *(const bf16x8*)&Ap[j * 8]);
        const __bf16* Wp = Wo + (size_t)wrow * 128 + wcol;
#pragma unroll
        for (int j = 0; j < 4; ++j)
            st8(&Ws[wrow][wcol + j * 8], *(const bf16x8*)&Wp[j * 8]);
    }
    __syncthreads();
    int lane = t & 63, wv = t >> 6;
    int l15 = lane & 15, quad = lane >> 4;
    int nh = wv & 1, mh = wv >> 1;   // mh 0..3: rows mh*16..+15
    f32x4 acc[4];

    // ---------- phase A: out-proj ----------
#pragma unroll
    for (int i = 0; i < 4; ++i) acc[i] = (f32x4){0.f, 0.f, 0.f, 0.f};
#pragma unroll
    for (int kc = 0; kc < 4; ++kc) {
        bf16x8 aw[4], ba;
#pragma unroll
        for (int nc = 0; nc < 4; ++nc)
            aw[nc] = ld8(&Ws[nh * 64 + nc * 16 + l15][kc * 32 + quad * 8]);
        ba = ld8(&As[mh * 16 + l15][kc * 32 + quad * 8]);
#pragma unroll
        for (int nc = 0; nc < 4; ++nc)
            acc[nc] = MFMA16(aw[nc], ba, acc[nc], 0, 0, 0);
    }
    float s1 = 0.f, s2 = 0.f;
    int m = m0 + mh * 16 + l15;
#pragma unroll
    for (int nc = 0; nc < 4; ++nc) {
        float4 bv = *(const float4*)&ob[nh * 64 + nc * 16 + quad * 4];
        bf16x4 rv = *(const bf16x4*)&hb[(size_t)m * 128 + nh * 64 + nc * 16 + quad * 4];
        acc[nc][0] += bv.x + (float)rv[0];
        acc[nc][1] += bv.y + (float)rv[1];
        acc[nc][2] += bv.z + (float)rv[2];
        acc[nc][3] += bv.w + (float)rv[3];
#pragma unroll
        for (int i = 0; i < 4; ++i) {
            s1 += acc[nc][i];
            s2 += acc[nc][i] * acc[nc][i];
        }
    }
    s1 += __shfl_xor(s1, 16); s1 += __shfl_xor(s1, 32);
    s2 += __shfl_xor(s2, 16); s2 += __shfl_xor(s2, 32);
    if (quad == 0) {
        red[nh][mh * 16 + l15][0] = s1;
        red[nh][mh * 16 + l15][1] = s2;
    }
    __syncthreads();
    float mu, rs;
    {
        int r = mh * 16 + l15;
        float S1 = red[0][r][0] + red[1][r][0];
        float S2 = red[0][r][1] + red[1][r][1];
        mu = S1 * (1.f / 128.f);
        float var = S2 * (1.f / 128.f) - mu * mu;
        rs = rsqrtf(var + EPS);
    }
    bf16x4 res2[4];
#pragma unroll
    for (int nc = 0; nc < 4; ++nc) {
        float4 gv = *(const float4*)&g1[nh * 64 + nc * 16 + quad * 4];
        float4 bb = *(const float4*)&bt1[nh * 64 + nc * 16 + quad * 4];
        float o0 = (acc[nc][0] - mu) * rs * gv.x + bb.x;
        float o1 = (acc[nc][1] - mu) * rs * gv.y + bb.y;
        float o2 = (acc[nc][2] - mu) * rs * gv.z + bb.z;
        float o3 = (acc[nc][3] - mu) * rs * gv.w + bb.w;
        bf16x4 xb;
        xb[0] = (__bf16)o0; xb[1] = (__bf16)o1;
        xb[2] = (__bf16)o2; xb[3] = (__bf16)o3;
        res2[nc] = xb;
        *(bf16x4*)&As[mh * 16 + l15][nh * 64 + nc * 16 + quad * 4] = xb;
    }
    {
        const __bf16* Wp = W1 + (size_t)wrow * 128 + wcol;
#pragma unroll
        for (int j = 0; j < 4; ++j)
            st8(&Ws[wrow][wcol + j * 8], *(const bf16x8*)&Wp[j * 8]);
    }
    __syncthreads();

    // ---------- phase B: FFN1 ----------
#pragma unroll
    for (int i = 0; i < 4; ++i) acc[i] = (f32x4){0.f, 0.f, 0.f, 0.f};
#pragma unroll
    for (int kc = 0; kc < 4; ++kc) {
        bf16x8 aw[4], ba;
#pragma unroll
        for (int nc = 0; nc < 4; ++nc)
            aw[nc] = ld8(&Ws[nh * 64 + nc * 16 + l15][kc * 32 + quad * 8]);
        ba = ld8(&As[mh * 16 + l15][kc * 32 + quad * 8]);
#pragma unroll
        for (int nc = 0; nc < 4; ++nc)
            acc[nc] = MFMA16(aw[nc], ba, acc[nc], 0, 0, 0);
    }
    __syncthreads();
#pragma unroll
    for (int nc = 0; nc < 4; ++nc) {
        float4 bv = *(const float4*)&b1v[nh * 64 + nc * 16 + quad * 4];
        float v0 = fmaxf(acc[nc][0] + bv.x, 0.f);
        float v1 = fmaxf(acc[nc][1] + bv.y, 0.f);
        float v2 = fmaxf(acc[nc][2] + bv.z, 0.f);
        float v3 = fmaxf(acc[nc][3] + bv.w, 0.f);
        uint2 u; u.x = pk2(v0, v1); u.y = pk2(v2, v3);
        *(uint2*)&As[mh * 16 + l15][nh * 64 + nc * 16 + quad * 4] = u;
    }
    {
        const __bf16* Wp = W2 + (size_t)wrow * 128 + wcol;
#pragma unroll
        for (int j = 0; j < 4; ++j)
            st8(&Ws[wrow][wcol + j * 8], *(const bf16x8*)&Wp[j * 8]);
    }
    __syncthreads();

    // ---------- phase C: FFN2 + res2 + LN2 ----------
#pragma unroll
    for (int i = 0; i < 4; ++i) acc[i] = (f32x4){0.f, 0.f, 0.f, 0.f};
#pragma unroll
    for (int kc = 0; kc < 4; ++kc) {
        bf16x8 aw[4], ba;
#pragma unroll
        for (int nc = 0; nc < 4; ++nc)
            aw[nc] = ld8(&Ws[nh * 64 + nc * 16 + l15][kc * 32 + quad * 8]);
        ba = ld8(&As[mh * 16 + l15][kc * 32 + quad * 8]);
#pragma unroll
        for (int nc = 0; nc < 4; ++nc)
            acc[nc] = MFMA16(aw[nc], ba, acc[nc], 0, 0, 0);
    }
    s1 = 0.f; s2 = 0.f;
#pragma unroll
    for (int nc = 0; nc < 4; ++nc) {
        float4 bv = *(const float4*)&b2v[nh * 64 + nc * 16 + quad * 4];
        acc[nc][0] += bv.x + (float)res2[nc][0];
        acc[nc][1] += bv.y + (float)res2[nc][1];
        acc[nc][2] += bv.z + (float)res2[nc][2];
        acc[nc][3] += bv.w + (float)res2[nc][3];
#pragma unroll
        for (int i = 0; i < 4; ++i) {
            s1 += acc[nc][i];
            s2 += acc[nc][i] * acc[nc][i];
        }
    }
    s1 += __shfl_xor(s1, 16); s1 += __shfl_xor(s1, 32);
    s2 += __shfl_xor(s2, 16); s2 += __shfl_xor(s2, 32);
    if (quad == 0) {
        red[nh][mh * 16 + l15][0] = s1;
        red[nh][mh * 16 + l15][1] = s2;
    }
    __syncthreads();
    {
        int r = mh * 16 + l15;
        float S1 = red[0][r][0] + red[1][r][0];
        float S2 = red[0][r][1] + red[1][r][1];
        mu = S1 * (1.f / 128.f);
        float var = S2 * (1.f / 128.f) - mu * mu;
        rs = rsqrtf(var + EPS);
    }
#pragma unroll
    for (int nc = 0; nc < 4; ++nc) {
        float4 gv = *(const float4*)&g2[nh * 64 + nc * 16 + quad * 4];
        float4 bb = *(const float4*)&bt2[nh * 64 + nc * 16 + quad * 4];
        float o0 = (acc[nc][0] - mu) * rs * gv.x + bb.x;
        float o1 = (acc[nc][1] - mu) * rs * gv.y + bb.y;
        float o2 = (acc[nc][2] - mu) * rs * gv.z + bb.z;
        float o3 = (acc[nc][3] - mu) * rs * gv.w + bb.w;
        uint2 u; u.x = pk2(o0, o1); u.y = pk2(o2, o3);
        *(uint2*)&hb[(size_t)m * 128 + nh * 64 + nc * 16 + quad * 4] = u;
    }
}

// ---------------- masked sum pool stage 1 (bf16 h) ----------------
__global__ __launch_bounds__(128) void k_pool1(const __bf16* __restrict__ h,
        const float* __restrict__ mask, float* __restrict__ part)
{
    int bx = blockIdx.x;
    int b = bx >> 3, ch = bx & 7, t = threadIdx.x;
    float acc = 0.f;
    const __bf16* hp = h + (size_t)(b * S + ch * 128) * E + t;
    const float* mp = mask + b * S + ch * 128;
    for (int s = 0; s < 128; ++s) acc += (float)hp[(size_t)s * E] * mp[s];
    part[(size_t)bx * E + t] = acc;
}

// ---------------- fused head: pool2 + cls1..3 + final sigmoid ----------------
__global__ __launch_bounds__(256) void k_head(const float* __restrict__ part,
        const float* __restrict__ cw1, const float* __restrict__ cb1,
        const float* __restrict__ cw2, const float* __restrict__ cb2,
        const float* __restrict__ cw3, const float* __restrict__ cb3,
        const float* __restrict__ cw4, const float* __restrict__ cb4,
        float* __restrict__ out)
{
    int b = blockIdx.x, t = threadIdx.x;
    __shared__ float p[128], za[256], zb[256];
    __shared__ float red4[4];
    if (t < 128) {
        float a = 0.f;
#pragma unroll
        for (int c = 0; c < 8; ++c) a += part[(size_t)(b * 8 + c) * 128 + t];
        p[t] = a;
    }
    __syncthreads();
    float a1 = cb1[t];
    for (int k = 0; k < 128; ++k) a1 += p[k] * cw1[t * 128 + k];
    za[t] = fmaxf(a1, 0.f);
    __syncthreads();
    float a2 = cb2[t];
    for (int k = 0; k < 256; ++k) a2 += za[k] * cw2[t * 256 + k];
    zb[t] = fmaxf(a2, 0.f);
    __syncthreads();
    float a3 = cb3[t];
    for (int k = 0; k < 256; ++k) a3 += zb[k] * cw3[t * 256 + k];
    float z3 = fmaxf(a3, 0.f);
    float prt = z3 * cw4[t];
#pragma unroll
    for (int o2 = 32; o2; o2 >>= 1) prt += __shfl_xor(prt, o2);
    if ((t & 63) == 0) red4[t >> 6] = prt;
    __syncthreads();
    if (t == 0) {
        float sum = red4[0] + red4[1] + red4[2] + red4[3] + cb4[0];
        out[b] = 1.f / (1.f + __expf(-sum));
    }
}

extern "C" void kernel_launch(void* const* d_in, const int* in_sizes, int n_in,
                              void* d_out, int out_size, void* d_ws, size_t ws_size,
                              hipStream_t stream)
{
    const float* x     = (const float*)d_in[0];
    const float* mask  = (const float*)d_in[1];
    const float* emb_w = (const float*)d_in[2];
    const float* emb_b = (const float*)d_in[3];
    const float* ipw   = (const float*)d_in[4];
    const float* ipb   = (const float*)d_in[5];
    const float* ow    = (const float*)d_in[6];
    const float* ob    = (const float*)d_in[7];
    const float* ln1g  = (const float*)d_in[8];
    const float* ln1b  = (const float*)d_in[9];
    const float* ln2g  = (const float*)d_in[10];
    const float* ln2b  = (const float*)d_in[11];
    const float* w1    = (const float*)d_in[12];
    const float* fb1   = (const float*)d_in[13];
    const float* w2    = (const float*)d_in[14];
    const float* fb2   = (const float*)d_in[15];
    const float* cw1   = (const float*)d_in[16];
    const float* cb1   = (const float*)d_in[17];
    const float* cw2   = (const float*)d_in[18];
    const float* cb2   = (const float*)d_in[19];
    const float* cw3   = (const float*)d_in[20];
    const float* cb3   = (const float*)d_in[21];
    const float* cw4   = (const float*)d_in[22];
    const float* cb4   = (const float*)d_in[23];

    char* p = (char*)d_ws;
    __bf16* hb   = (__bf16*)p;   p += (size_t)ROWS * E * 2;        // 8 MB bf16 stream
    p += (size_t)ROWS * 256 * 2;                                   // (qkb slot, unused)
    p += (size_t)ROWS * 32 * 4 * 2 / 4;                            // (vtb slot, unused)
    __bf16* t0b  = (__bf16*)p;   p += (size_t)ROWS * E * 2;        // 8 MB attn out
    __bf16* wb   = (__bf16*)p;   p += (size_t)(N_IPW + 3 * N_SQ) * 2;
    float* part  = (float*)p;    p += (size_t)B * 8 * E * 4;

    __bf16* wb_ipw = wb;
    __bf16* wb_ow  = wb + N_IPW;
    __bf16* wb_w1  = wb_ow + N_SQ;
    __bf16* wb_w2  = wb_w1 + N_SQ;

    k_embedcvt<<<NCVT + ROWS / 16, 256, 0, stream>>>(
        ipw, ow, w1, w2, wb, x, emb_w, emb_b, hb);
    for (int L = 0; L < 3; ++L) {
        k_qkvattn<<<B * NH * 2, 1024, 0, stream>>>(
            hb, wb_ipw + (size_t)L * 384 * 128, ipb + L * 384, t0b);
        k_layer2<<<ROWS / 64, 512, 0, stream>>>(
            t0b, wb_ow + (size_t)L * 128 * 128, ob + L * 128,
            ln1g + L * E, ln1b + L * E,
            wb_w1 + (size_t)L * 128 * 128, fb1 + L * 128,
            wb_w2 + (size_t)L * 128 * 128, fb2 + L * 128,
            ln2g + L * E, ln2b + L * E, hb);
    }
    k_pool1<<<B * 8, 128, 0, stream>>>(hb, mask, part);
    k_head<<<B, 256, 0, stream>>>(part, cw1, cb1, cw2, cb2, cw3, cb3, cw4, cb4,
                                  (float*)d_out);
}

// Round 3
// 291.726 us; speedup vs baseline: 1.0848x; 1.0848x over previous
//
#include <hip/hip_runtime.h>
#include <hip/hip_bf16.h>
#include <math.h>

#define B 32
#define S 1024
#define IN_DIM 16
#define E 128
#define NH 4
#define DH 32
#define HDIM 256
#define ROWS (B*S)   /* 32768 */
#define EPS 1e-5f

#define N_IPW (3*384*128)
#define N_SQ  (3*128*128)
#define NCVT ((N_IPW + 3*N_SQ) / 256)   /* 1152 cvt blocks */

typedef __bf16 bf16x8 __attribute__((ext_vector_type(8)));
typedef __bf16 bf16x4 __attribute__((ext_vector_type(4)));
typedef __bf16 bf16x2 __attribute__((ext_vector_type(2)));
typedef float f32x4 __attribute__((ext_vector_type(4)));
typedef float f32x16 __attribute__((ext_vector_type(16)));

#define MFMA16 __builtin_amdgcn_mfma_f32_16x16x32_bf16
#define MFMA32 __builtin_amdgcn_mfma_f32_32x32x16_bf16

union BF2U { bf16x2 b; unsigned int u; };
__device__ inline unsigned int pk2(float a, float b) {
    BF2U x; x.b[0] = (__bf16)a; x.b[1] = (__bf16)b; return x.u;
}

// 16B logical access as two 8B LDS ops (rows padded to RP%8==4 elems are only
// 8B-aligned; RP%8==4 makes every hot pattern exactly 4 dwords/bank).
union U8 { bf16x8 v8; bf16x4 v4[2]; unsigned u4[4]; };
__device__ inline void st8(__bf16* p, bf16x8 v) {
    U8 u; u.v8 = v;
    *(bf16x4*)p = u.v4[0];
    *(bf16x4*)(p + 4) = u.v4[1];
}
__device__ inline bf16x8 ld8(const __bf16* p) {
    U8 u;
    u.v4[0] = *(const bf16x4*)p;
    u.v4[1] = *(const bf16x4*)(p + 4);
    return u.v8;
}

// ---------------- fused weight-cvt + embed ----------------
__global__ __launch_bounds__(256) void k_embedcvt(
        const float* __restrict__ ipw, const float* __restrict__ ow,
        const float* __restrict__ w1, const float* __restrict__ w2,
        __bf16* __restrict__ wbo,
        const float* __restrict__ x, const float* __restrict__ W,
        const float* __restrict__ bias, __bf16* __restrict__ hb)
{
    int t = threadIdx.x;
    if (blockIdx.x < NCVT) {
        int i = blockIdx.x * 256 + t;
        float v;
        if (i < N_IPW) v = ipw[i];
        else if (i < N_IPW + N_SQ) v = ow[i - N_IPW];
        else if (i < N_IPW + 2 * N_SQ) v = w1[i - N_IPW - N_SQ];
        else v = w2[i - N_IPW - 2 * N_SQ];
        wbo[i] = (__bf16)v;
        return;
    }
    int row0 = (blockIdx.x - NCVT) * 16;
    __shared__ float xs[16][16];
    xs[t >> 4][t & 15] = x[(row0 + (t >> 4)) * IN_DIM + (t & 15)];
    __syncthreads();
    int sub = t >> 7, tc = t & 127;
    float w[16];
#pragma unroll
    for (int i = 0; i < 16; ++i) w[i] = W[tc * 16 + i];
    float bb = bias[tc];
#pragma unroll
    for (int rr = 0; rr < 8; ++rr) {
        int lr = sub * 8 + rr;
        float acc = bb;
#pragma unroll
        for (int i = 0; i < 16; ++i) acc += xs[lr][i] * w[i];
        hb[(size_t)(row0 + lr) * E + tc] = (__bf16)fmaxf(acc, 0.f);
    }
}

// ---------------- fused QKV-projection + flash attention (R3: 32x32 MFMA) ----------------
// 8 waves x 64 q-rows. Phase-3 transpose eliminated: S^T = mfma32(K,Q) leaves
// lane (hi,q) holding S[k][q] for k = 4hi+{0-3,8-11,16-19,24-27}; packed to
// bf16 these regs ARE the 32x32 A-frag for PV if V's B-frag is read with the
// matching permuted k-order (two b64 reads at +0/+8 — same op count as ld8).
// No Pm round-trip, no fences, no cross-lane in the k-loop. Row-sum l via
// ones-MFMA32 (lands in o's C-layout). LDS/wave/c-chunk: 24KB -> 8KB.
__global__ __launch_bounds__(512, 2) void k_qkvattn(
        const __bf16* __restrict__ hb, const __bf16* __restrict__ Wip,
        const float* __restrict__ bip, __bf16* __restrict__ O)
{
    __shared__ __attribute__((aligned(16))) __bf16 Ksh[1024][36];
    __shared__ __attribute__((aligned(16))) __bf16 Vsh[32][1036];
    __shared__ __attribute__((aligned(16))) __bf16 Pm[8][32][36];

    int t = threadIdx.x, lane = t & 63, wv = t >> 6;   // wv 0..7
    int l15 = lane & 15, quad = lane >> 4;
    int l31 = lane & 31, hi = lane >> 5;
    // XCD grouping: all 8 blocks sharing a b-panel land on the same XCD.
    int lb = ((blockIdx.x & 7) << 5) | (blockIdx.x >> 3);
    int half = lb & 1, bh = lb >> 1;
    int hh = bh & 3, b = bh >> 2;

    const __bf16* hpanel = hb + (size_t)b * S * E;

    // scale * log2(e) * 2^23 (Schraudolph pre-scale)
    const float qscale = 0.1767766952966369f * 1.4426950408889634f * 8388608.0f;
    const float C2 = 1065101558.0f;   // (127<<23) - 0.03*2^23
    f32x16 cinit16, z16;
#pragma unroll
    for (int i = 0; i < 16; ++i) { cinit16[i] = C2; z16[i] = 0.f; }

    // ---------- phase 1: Q for this wave's 64 rows, 32x32 path ----------
    // D[q][d]: col=l31=d (full head dim), rows q via regs. One-time LDS
    // transpose to B-frag layout (lane=q, regs=d).
    bf16x8 bQ[2][2];
    {
        bf16x8 bWq[8];
#pragma unroll
        for (int ch = 0; ch < 8; ++ch)
            bWq[ch] = *(const bf16x8*)&Wip[(size_t)(hh*32 + l31)*128 + ch*16 + hi*8];
        float bq = bip[hh*32 + l31];
#pragma unroll
        for (int qt = 0; qt < 2; ++qt) {
            int qrow0 = half*512 + wv*64 + qt*32;
            f32x16 aq = z16;
#pragma unroll
            for (int ch = 0; ch < 8; ++ch) {
                bf16x8 ah = *(const bf16x8*)&hpanel[(size_t)(qrow0 + l31)*128 + ch*16 + hi*8];
                aq = MFMA32(ah, bWq[ch], aq, 0, 0, 0);
            }
#pragma unroll
            for (int r = 0; r < 16; ++r) {
                int q = (r & 3) + 8*(r >> 2) + 4*hi;
                Pm[wv][q][l31] = (__bf16)((aq[r] + bq) * qscale);
            }
            __asm__ __volatile__("" ::: "memory");
            bQ[qt][0] = ld8(&Pm[wv][l31][hi*8]);
            bQ[qt][1] = ld8(&Pm[wv][l31][16 + hi*8]);
            __asm__ __volatile__("" ::: "memory");
        }
    }

    // ---------- phase 2: K,V projection into LDS (barrier-free, 16x16) ----------
    {
        bf16x8 bWk[2][4], bWv[2][4];
#pragma unroll
        for (int df = 0; df < 2; ++df)
#pragma unroll
            for (int kc = 0; kc < 4; ++kc) {
                bWk[df][kc] = *(const bf16x8*)&Wip[(size_t)(128 + hh*32 + df*16 + l15)*128 + kc*32 + quad*8];
                bWv[df][kc] = *(const bf16x8*)&Wip[(size_t)(256 + hh*32 + df*16 + l15)*128 + kc*32 + quad*8];
            }
        float bk0 = bip[128 + hh*32 + l15],  bk1 = bip[128 + hh*32 + 16 + l15];
        float bvb0 = bip[256 + hh*32 + l15], bvb1 = bip[256 + hh*32 + 16 + l15];
        int srow = wv*16 + l15;
        bf16x8 af[4], ag[4];
#pragma unroll
        for (int kc = 0; kc < 4; ++kc)
            af[kc] = *(const bf16x8*)&hpanel[(size_t)srow*128 + kc*32 + quad*8];
        const f32x4 z4 = {0.f, 0.f, 0.f, 0.f};
        for (int c = 0; c < 8; ++c) {
            if (c < 7) {
#pragma unroll
                for (int kc = 0; kc < 4; ++kc)
                    ag[kc] = *(const bf16x8*)&hpanel[(size_t)((c+1)*128 + srow)*128 + kc*32 + quad*8];
            }
            f32x4 k0 = z4, k1 = z4, v0 = z4, v1 = z4;
#pragma unroll
            for (int kc = 0; kc < 4; ++kc) {
                k0 = MFMA16(af[kc], bWk[0][kc], k0, 0, 0, 0);
                k1 = MFMA16(af[kc], bWk[1][kc], k1, 0, 0, 0);
                v0 = MFMA16(af[kc], bWv[0][kc], v0, 0, 0, 0);
                v1 = MFMA16(af[kc], bWv[1][kc], v1, 0, 0, 0);
            }
            int s0 = c*128 + wv*16 + quad*4;
#pragma unroll
            for (int r = 0; r < 4; ++r) {
                Ksh[s0 + r][l15]      = (__bf16)(k0[r] + bk0);
                Ksh[s0 + r][16 + l15] = (__bf16)(k1[r] + bk1);
            }
            uint2 u0, u1;
            u0.x = pk2(v0[0] + bvb0, v0[1] + bvb0);
            u0.y = pk2(v0[2] + bvb0, v0[3] + bvb0);
            u1.x = pk2(v1[0] + bvb1, v1[1] + bvb1);
            u1.y = pk2(v1[2] + bvb1, v1[3] + bvb1);
            *(uint2*)&Vsh[l15][s0] = u0;
            *(uint2*)&Vsh[16 + l15][s0] = u1;
#pragma unroll
            for (int kc = 0; kc < 4; ++kc) af[kc] = ag[kc];
        }
    }
    __syncthreads();

    // ---------- phase 3: attention, fence-free ----------
    bf16x8 vones;
#pragma unroll
    for (int j = 0; j < 8; ++j) vones[j] = (__bf16)1.0f;
    f32x16 o[2], ol[2];
    o[0] = z16; o[1] = z16; ol[0] = z16; ol[1] = z16;

    for (int c = 0; c < 16; ++c) {
        bf16x8 aK[2][2];
#pragma unroll
        for (int sub = 0; sub < 2; ++sub)
#pragma unroll
            for (int dh = 0; dh < 2; ++dh)
                aK[sub][dh] = ld8(&Ksh[c*64 + sub*32 + l31][dh*16 + hi*8]);
        bf16x8 bVf[4];
#pragma unroll
        for (int ch = 0; ch < 4; ++ch) {
            U8 u;
            const __bf16* vp = &Vsh[l31][c*64 + ch*16 + hi*4];
            u.v4[0] = *(const bf16x4*)vp;        // k = ch*16 + 4hi + 0..3
            u.v4[1] = *(const bf16x4*)(vp + 8);  // k = ch*16 + 8 + 4hi + 0..3
            bVf[ch] = u.v8;
        }
#pragma unroll
        for (int qt = 0; qt < 2; ++qt) {
#pragma unroll
            for (int sub = 0; sub < 2; ++sub) {
                f32x16 acc = cinit16;
                acc = MFMA32(aK[sub][0], bQ[qt][0], acc, 0, 0, 0);
                acc = MFMA32(aK[sub][1], bQ[qt][1], acc, 0, 0, 0);
                // S[k][q] at lane(hi,q): k = 4hi + {0-3,8-11} (+16 for g=1).
                // Packed dwords are directly the PV A-frag (k-order matches
                // bVf's permuted reads).
#pragma unroll
                for (int g = 0; g < 2; ++g) {
                    U8 u;
#pragma unroll
                    for (int r = 0; r < 4; ++r) {
                        int ia = (int)acc[g*8 + 2*r];
                        int ib = (int)acc[g*8 + 2*r + 1];
                        u.u4[r] = __builtin_amdgcn_perm((unsigned)ib, (unsigned)ia, 0x07060302u);
                    }
                    bf16x8 ap = u.v8;
                    int ch = sub*2 + g;
                    o[qt]  = MFMA32(ap, bVf[ch], o[qt], 0, 0, 0);
                    ol[qt] = MFMA32(ap, vones,  ol[qt], 0, 0, 0);
                }
            }
        }
    }

    // ---------- epilogue ----------
#pragma unroll
    for (int qt = 0; qt < 2; ++qt)
#pragma unroll
        for (int r = 0; r < 16; ++r) {
            float linv = 1.f / ol[qt][r];
            int q = (r & 3) + 8*(r >> 2) + 4*hi;
            int row = half*512 + wv*64 + qt*32 + q;
            O[((size_t)(b * S) + row) * E + hh*32 + l31] = (__bf16)(o[qt][r] * linv);
        }
}

// ---------------- mega-fused: out-proj + res + LN1 + FFN1 + FFN2 + res + LN2 ----------------
// 512 threads = 8 waves; each wave 16 rows x 64 cols. Grid 512 -> 2 blocks/CU
// -> 16 waves/CU = 4 waves/SIMD.
__global__ __launch_bounds__(512, 4) void k_layer2(const __bf16* __restrict__ t0b,
        const __bf16* __restrict__ Wo, const float* __restrict__ ob,
        const float* __restrict__ g1, const float* __restrict__ bt1,
        const __bf16* __restrict__ W1, const float* __restrict__ b1v,
        const __bf16* __restrict__ W2, const float* __restrict__ b2v,
        const float* __restrict__ g2, const float* __restrict__ bt2,
        __bf16* __restrict__ hb)
{
    __shared__ __attribute__((aligned(16))) __bf16 As[64][132];
    __shared__ __attribute__((aligned(16))) __bf16 Ws[128][132];
    __shared__ float red[2][64][2];
    int t = threadIdx.x;
    int m0 = blockIdx.x * 64;
    int arow = t >> 3, acol = (t & 7) * 16;
    int wrow = t >> 2, wcol = (t & 3) * 32;
    {
        const __bf16* Ap = t0b + (size_t)(m0 + arow) * 128 + acol;
#pragma unroll
        for (int j = 0; j < 2; ++j)
            st8(&As[arow][acol + j * 8], *(const bf16x8*)&Ap[j * 8]);
        const __bf16* Wp = Wo + (size_t)wrow * 128 + wcol;
#pragma unroll
        for (int j = 0; j < 4; ++j)
            st8(&Ws[wrow][wcol + j * 8], *(const bf16x8*)&Wp[j * 8]);
    }
    __syncthreads();
    int lane = t & 63, wv = t >> 6;
    int l15 = lane & 15, quad = lane >> 4;
    int nh = wv & 1, mh = wv >> 1;   // mh 0..3: rows mh*16..+15
    f32x4 acc[4];

    // ---------- phase A: out-proj ----------
#pragma unroll
    for (int i = 0; i < 4; ++i) acc[i] = (f32x4){0.f, 0.f, 0.f, 0.f};
#pragma unroll
    for (int kc = 0; kc < 4; ++kc) {
        bf16x8 aw[4], ba;
#pragma unroll
        for (int nc = 0; nc < 4; ++nc)
            aw[nc] = ld8(&Ws[nh * 64 + nc * 16 + l15][kc * 32 + quad * 8]);
        ba = ld8(&As[mh * 16 + l15][kc * 32 + quad * 8]);
#pragma unroll
        for (int nc = 0; nc < 4; ++nc)
            acc[nc] = MFMA16(aw[nc], ba, acc[nc], 0, 0, 0);
    }
    float s1 = 0.f, s2 = 0.f;
    int m = m0 + mh * 16 + l15;
#pragma unroll
    for (int nc = 0; nc < 4; ++nc) {
        float4 bv = *(const float4*)&ob[nh * 64 + nc * 16 + quad * 4];
        bf16x4 rv = *(const bf16x4*)&hb[(size_t)m * 128 + nh * 64 + nc * 16 + quad * 4];
        acc[nc][0] += bv.x + (float)rv[0];
        acc[nc][1] += bv.y + (float)rv[1];
        acc[nc][2] += bv.z + (float)rv[2];
        acc[nc][3] += bv.w + (float)rv[3];
#pragma unroll
        for (int i = 0; i < 4; ++i) {
            s1 += acc[nc][i];
            s2 += acc[nc][i] * acc[nc][i];
        }
    }
    s1 += __shfl_xor(s1, 16); s1 += __shfl_xor(s1, 32);
    s2 += __shfl_xor(s2, 16); s2 += __shfl_xor(s2, 32);
    if (quad == 0) {
        red[nh][mh * 16 + l15][0] = s1;
        red[nh][mh * 16 + l15][1] = s2;
    }
    __syncthreads();
    float mu, rs;
    {
        int r = mh * 16 + l15;
        float S1 = red[0][r][0] + red[1][r][0];
        float S2 = red[0][r][1] + red[1][r][1];
        mu = S1 * (1.f / 128.f);
        float var = S2 * (1.f / 128.f) - mu * mu;
        rs = rsqrtf(var + EPS);
    }
    bf16x4 res2[4];
#pragma unroll
    for (int nc = 0; nc < 4; ++nc) {
        float4 gv = *(const float4*)&g1[nh * 64 + nc * 16 + quad * 4];
        float4 bb = *(const float4*)&bt1[nh * 64 + nc * 16 + quad * 4];
        float o0 = (acc[nc][0] - mu) * rs * gv.x + bb.x;
        float o1 = (acc[nc][1] - mu) * rs * gv.y + bb.y;
        float o2 = (acc[nc][2] - mu) * rs * gv.z + bb.z;
        float o3 = (acc[nc][3] - mu) * rs * gv.w + bb.w;
        bf16x4 xb;
        xb[0] = (__bf16)o0; xb[1] = (__bf16)o1;
        xb[2] = (__bf16)o2; xb[3] = (__bf16)o3;
        res2[nc] = xb;
        *(bf16x4*)&As[mh * 16 + l15][nh * 64 + nc * 16 + quad * 4] = xb;
    }
    {
        const __bf16* Wp = W1 + (size_t)wrow * 128 + wcol;
#pragma unroll
        for (int j = 0; j < 4; ++j)
            st8(&Ws[wrow][wcol + j * 8], *(const bf16x8*)&Wp[j * 8]);
    }
    __syncthreads();

    // ---------- phase B: FFN1 ----------
#pragma unroll
    for (int i = 0; i < 4; ++i) acc[i] = (f32x4){0.f, 0.f, 0.f, 0.f};
#pragma unroll
    for (int kc = 0; kc < 4; ++kc) {
        bf16x8 aw[4], ba;
#pragma unroll
        for (int nc = 0; nc < 4; ++nc)
            aw[nc] = ld8(&Ws[nh * 64 + nc * 16 + l15][kc * 32 + quad * 8]);
        ba = ld8(&As[mh * 16 + l15][kc * 32 + quad * 8]);
#pragma unroll
        for (int nc = 0; nc < 4; ++nc)
            acc[nc] = MFMA16(aw[nc], ba, acc[nc], 0, 0, 0);
    }
    __syncthreads();
#pragma unroll
    for (int nc = 0; nc < 4; ++nc) {
        float4 bv = *(const float4*)&b1v[nh * 64 + nc * 16 + quad * 4];
        float v0 = fmaxf(acc[nc][0] + bv.x, 0.f);
        float v1 = fmaxf(acc[nc][1] + bv.y, 0.f);
        float v2 = fmaxf(acc[nc][2] + bv.z, 0.f);
        float v3 = fmaxf(acc[nc][3] + bv.w, 0.f);
        uint2 u; u.x = pk2(v0, v1); u.y = pk2(v2, v3);
        *(uint2*)&As[mh * 16 + l15][nh * 64 + nc * 16 + quad * 4] = u;
    }
    {
        const __bf16* Wp = W2 + (size_t)wrow * 128 + wcol;
#pragma unroll
        for (int j = 0; j < 4; ++j)
            st8(&Ws[wrow][wcol + j * 8], *(const bf16x8*)&Wp[j * 8]);
    }
    __syncthreads();

    // ---------- phase C: FFN2 + res2 + LN2 ----------
#pragma unroll
    for (int i = 0; i < 4; ++i) acc[i] = (f32x4){0.f, 0.f, 0.f, 0.f};
#pragma unroll
    for (int kc = 0; kc < 4; ++kc) {
        bf16x8 aw[4], ba;
#pragma unroll
        for (int nc = 0; nc < 4; ++nc)
            aw[nc] = ld8(&Ws[nh * 64 + nc * 16 + l15][kc * 32 + quad * 8]);
        ba = ld8(&As[mh * 16 + l15][kc * 32 + quad * 8]);
#pragma unroll
        for (int nc = 0; nc < 4; ++nc)
            acc[nc] = MFMA16(aw[nc], ba, acc[nc], 0, 0, 0);
    }
    s1 = 0.f; s2 = 0.f;
#pragma unroll
    for (int nc = 0; nc < 4; ++nc) {
        float4 bv = *(const float4*)&b2v[nh * 64 + nc * 16 + quad * 4];
        acc[nc][0] += bv.x + (float)res2[nc][0];
        acc[nc][1] += bv.y + (float)res2[nc][1];
        acc[nc][2] += bv.z + (float)res2[nc][2];
        acc[nc][3] += bv.w + (float)res2[nc][3];
#pragma unroll
        for (int i = 0; i < 4; ++i) {
            s1 += acc[nc][i];
            s2 += acc[nc][i] * acc[nc][i];
        }
    }
    s1 += __shfl_xor(s1, 16); s1 += __shfl_xor(s1, 32);
    s2 += __shfl_xor(s2, 16); s2 += __shfl_xor(s2, 32);
    if (quad == 0) {
        red[nh][mh * 16 + l15][0] = s1;
        red[nh][mh * 16 + l15][1] = s2;
    }
    __syncthreads();
    {
        int r = mh * 16 + l15;
        float S1 = red[0][r][0] + red[1][r][0];
        float S2 = red[0][r][1] + red[1][r][1];
        mu = S1 * (1.f / 128.f);
        float var = S2 * (1.f / 128.f) - mu * mu;
        rs = rsqrtf(var + EPS);
    }
#pragma unroll
    for (int nc = 0; nc < 4; ++nc) {
        float4 gv = *(const float4*)&g2[nh * 64 + nc * 16 + quad * 4];
        float4 bb = *(const float4*)&bt2[nh * 64 + nc * 16 + quad * 4];
        float o0 = (acc[nc][0] - mu) * rs * gv.x + bb.x;
        float o1 = (acc[nc][1] - mu) * rs * gv.y + bb.y;
        float o2 = (acc[nc][2] - mu) * rs * gv.z + bb.z;
        float o3 = (acc[nc][3] - mu) * rs * gv.w + bb.w;
        uint2 u; u.x = pk2(o0, o1); u.y = pk2(o2, o3);
        *(uint2*)&hb[(size_t)m * 128 + nh * 64 + nc * 16 + quad * 4] = u;
    }
}

// ---------------- masked sum pool stage 1 (bf16 h) ----------------
__global__ __launch_bounds__(128) void k_pool1(const __bf16* __restrict__ h,
        const float* __restrict__ mask, float* __restrict__ part)
{
    int bx = blockIdx.x;
    int b = bx >> 3, ch = bx & 7, t = threadIdx.x;
    float acc = 0.f;
    const __bf16* hp = h + (size_t)(b * S + ch * 128) * E + t;
    const float* mp = mask + b * S + ch * 128;
    for (int s = 0; s < 128; ++s) acc += (float)hp[(size_t)s * E] * mp[s];
    part[(size_t)bx * E + t] = acc;
}

// ---------------- fused head: pool2 + cls1..3 + final sigmoid ----------------
__global__ __launch_bounds__(256) void k_head(const float* __restrict__ part,
        const float* __restrict__ cw1, const float* __restrict__ cb1,
        const float* __restrict__ cw2, const float* __restrict__ cb2,
        const float* __restrict__ cw3, const float* __restrict__ cb3,
        const float* __restrict__ cw4, const float* __restrict__ cb4,
        float* __restrict__ out)
{
    int b = blockIdx.x, t = threadIdx.x;
    __shared__ float p[128], za[256], zb[256];
    __shared__ float red4[4];
    if (t < 128) {
        float a = 0.f;
#pragma unroll
        for (int c = 0; c < 8; ++c) a += part[(size_t)(b * 8 + c) * 128 + t];
        p[t] = a;
    }
    __syncthreads();
    float a1 = cb1[t];
    for (int k = 0; k < 128; ++k) a1 += p[k] * cw1[t * 128 + k];
    za[t] = fmaxf(a1, 0.f);
    __syncthreads();
    float a2 = cb2[t];
    for (int k = 0; k < 256; ++k) a2 += za[k] * cw2[t * 256 + k];
    zb[t] = fmaxf(a2, 0.f);
    __syncthreads();
    float a3 = cb3[t];
    for (int k = 0; k < 256; ++k) a3 += zb[k] * cw3[t * 256 + k];
    float z3 = fmaxf(a3, 0.f);
    float prt = z3 * cw4[t];
#pragma unroll
    for (int o2 = 32; o2; o2 >>= 1) prt += __shfl_xor(prt, o2);
    if ((t & 63) == 0) red4[t >> 6] = prt;
    __syncthreads();
    if (t == 0) {
        float sum = red4[0] + red4[1] + red4[2] + red4[3] + cb4[0];
        out[b] = 1.f / (1.f + __expf(-sum));
    }
}

extern "C" void kernel_launch(void* const* d_in, const int* in_sizes, int n_in,
                              void* d_out, int out_size, void* d_ws, size_t ws_size,
                              hipStream_t stream)
{
    const float* x     = (const float*)d_in[0];
    const float* mask  = (const float*)d_in[1];
    const float* emb_w = (const float*)d_in[2];
    const float* emb_b = (const float*)d_in[3];
    const float* ipw   = (const float*)d_in[4];
    const float* ipb   = (const float*)d_in[5];
    const float* ow    = (const float*)d_in[6];
    const float* ob    = (const float*)d_in[7];
    const float* ln1g  = (const float*)d_in[8];
    const float* ln1b  = (const float*)d_in[9];
    const float* ln2g  = (const float*)d_in[10];
    const float* ln2b  = (const float*)d_in[11];
    const float* w1    = (const float*)d_in[12];
    const float* fb1   = (const float*)d_in[13];
    const float* w2    = (const float*)d_in[14];
    const float* fb2   = (const float*)d_in[15];
    const float* cw1   = (const float*)d_in[16];
    const float* cb1   = (const float*)d_in[17];
    const float* cw2   = (const float*)d_in[18];
    const float* cb2   = (const float*)d_in[19];
    const float* cw3   = (const float*)d_in[20];
    const float* cb3   = (const float*)d_in[21];
    const float* cw4   = (const float*)d_in[22];
    const float* cb4   = (const float*)d_in[23];

    char* p = (char*)d_ws;
    __bf16* hb   = (__bf16*)p;   p += (size_t)ROWS * E * 2;        // 8 MB bf16 stream
    p += (size_t)ROWS * 256 * 2;                                   // (qkb slot, unused)
    p += (size_t)ROWS * 32 * 4 * 2 / 4;                            // (vtb slot, unused)
    __bf16* t0b  = (__bf16*)p;   p += (size_t)ROWS * E * 2;        // 8 MB attn out
    __bf16* wb   = (__bf16*)p;   p += (size_t)(N_IPW + 3 * N_SQ) * 2;
    float* part  = (float*)p;    p += (size_t)B * 8 * E * 4;

    __bf16* wb_ipw = wb;
    __bf16* wb_ow  = wb + N_IPW;
    __bf16* wb_w1  = wb_ow + N_SQ;
    __bf16* wb_w2  = wb_w1 + N_SQ;

    k_embedcvt<<<NCVT + ROWS / 16, 256, 0, stream>>>(
        ipw, ow, w1, w2, wb, x, emb_w, emb_b, hb);
    for (int L = 0; L < 3; ++L) {
        k_qkvattn<<<B * NH * 2, 512, 0, stream>>>(
            hb, wb_ipw + (size_t)L * 384 * 128, ipb + L * 384, t0b);
        k_layer2<<<ROWS / 64, 512, 0, stream>>>(
            t0b, wb_ow + (size_t)L * 128 * 128, ob + L * 128,
            ln1g + L * E, ln1b + L * E,
            wb_w1 + (size_t)L * 128 * 128, fb1 + L * 128,
            wb_w2 + (size_t)L * 128 * 128, fb2 + L * 128,
            ln2g + L * E, ln2b + L * E, hb);
    }
    k_pool1<<<B * 8, 128, 0, stream>>>(hb, mask, part);
    k_head<<<B, 256, 0, stream>>>(part, cw1, cb1, cw2, cb2, cw3, cb3, cw4, cb4,
                                  (float*)d_out);
}